// Round 6
// baseline (96.614 us; speedup 1.0000x reference)
//
#include <hip/hip_runtime.h>

// Problem: B=4, C=19, H=1024, W=1024, N=500000
// out = mean_n [ log(sum_j exp(p_j)) - p_label ],  p = softmax(predict[b,:,r,c])
//
// Structure: (A) coalesced streaming pass computes nll for ALL 4M positions
// into a 16 MB table in d_ws (float4-vectorized), then (B) random 4B gather
// from the table (+block reduce) -- B's distinct-line footprint is ~3.4 MB
// per XCD, L2-resident during B, so table cache residency is a non-issue.
// (C) finalize.
//
// Round-5 lesson: nontemporal loads REGRESSED kernel A (87.8 -> 94.5 us);
// this round keeps float4 vectorization, drops all NT hints (single-variable
// A/B vs round 5).
//
// NOTE: harness ABI passes ALL integer inputs as int32.

#define CCH 19
#define BLOCK 256
#define POS_BITS 20               // H*W = 1<<20
#define TOTAL_POS (4 << POS_BITS) // B * H * W = 4M

__device__ __forceinline__ float nll_compute(float* __restrict__ x, int label)
{
    float m = x[0];
    #pragma unroll
    for (int j = 1; j < CCH; ++j) m = fmaxf(m, x[j]);

    float s = 0.0f, e_label = 0.0f;
    #pragma unroll
    for (int j = 0; j < CCH; ++j) {
        float e = __expf(x[j] - m);
        s += e;
        if (j == label) e_label = e;   // static j vs runtime label -> cndmask
        x[j] = e;
    }
    float inv = 1.0f / s;

    float s2 = 0.0f;
    #pragma unroll
    for (int j = 0; j < CCH; ++j) s2 += __expf(x[j] * inv);

    return __logf(s2) - e_label * inv;
}

// ---- kernel A: streamed nll table, 4 positions per thread ----
// grid*block*4 == TOTAL_POS exactly (1048576 threads = 4096 blocks) -> no bounds check
__global__ __launch_bounds__(BLOCK) void nll_table_v4(
    const float* __restrict__ predict,
    const int* __restrict__ target,
    float* __restrict__ table)
{
    int q = blockIdx.x * blockDim.x + threadIdx.x;   // quad index
    int i = q << 2;                                  // position index (b*HW + pos)
    int b = i >> POS_BITS;
    int pos = i & ((1 << POS_BITS) - 1);
    const float4* base =
        (const float4*)(predict + (((size_t)b * CCH) << POS_BITS) + (size_t)pos);

    // 19 channel loads, 16B each, normal caching (NT regressed in round 5)
    float xs[4][CCH];                    // statically indexed only -> registers
    #pragma unroll
    for (int j = 0; j < CCH; ++j) {
        float4 v = base[(size_t)j << 18];            // 4MB channel stride / 16B
        xs[0][j] = v.x; xs[1][j] = v.y; xs[2][j] = v.z; xs[3][j] = v.w;
    }
    int4 lb = *(const int4*)(target + i);

    float4 o;
    o.x = nll_compute(xs[0], lb.x);
    o.y = nll_compute(xs[1], lb.y);
    o.z = nll_compute(xs[2], lb.z);
    o.w = nll_compute(xs[3], lb.w);
    *(float4*)(table + i) = o;
}

// ---- kernel B: random 4B gather from 16MB table + block reduce ----
__global__ __launch_bounds__(BLOCK) void table_gather_kernel(
    const float* __restrict__ table,
    const int* __restrict__ loc_b,
    const int* __restrict__ loc_row,
    const int* __restrict__ loc_col,
    float* __restrict__ partial,
    int n)
{
    int i = blockIdx.x * blockDim.x + threadIdx.x;
    float nll = 0.0f;
    if (i < n) {
        int idx = (loc_b[i] << POS_BITS) + (loc_row[i] << 10) + loc_col[i];
        nll = table[idx];
    }
    __shared__ float red[BLOCK];
    red[threadIdx.x] = nll;
    __syncthreads();
    #pragma unroll
    for (int off = BLOCK / 2; off > 0; off >>= 1) {
        if (threadIdx.x < off) red[threadIdx.x] += red[threadIdx.x + off];
        __syncthreads();
    }
    if (threadIdx.x == 0) partial[blockIdx.x] = red[0];
}

// ---- fallback: direct random gather (round-2 path), used if ws too small ----
__global__ __launch_bounds__(BLOCK) void partial_loss_gather(
    const float* __restrict__ predict,
    const int* __restrict__ target,
    const int* __restrict__ loc_b,
    const int* __restrict__ loc_row,
    const int* __restrict__ loc_col,
    float* __restrict__ partial,
    int n)
{
    int i = blockIdx.x * blockDim.x + threadIdx.x;
    float nll = 0.0f;
    if (i < n) {
        int b = loc_b[i];
        int pos = (loc_row[i] << 10) + loc_col[i];
        const float* base = predict + (((size_t)b * CCH) << POS_BITS) + (size_t)pos;
        int label = target[((size_t)b << POS_BITS) + (size_t)pos];
        float x[CCH];
        #pragma unroll
        for (int j = 0; j < CCH; ++j) x[j] = base[(size_t)j << POS_BITS];
        nll = nll_compute(x, label);
    }
    __shared__ float red[BLOCK];
    red[threadIdx.x] = nll;
    __syncthreads();
    #pragma unroll
    for (int off = BLOCK / 2; off > 0; off >>= 1) {
        if (threadIdx.x < off) red[threadIdx.x] += red[threadIdx.x + off];
        __syncthreads();
    }
    if (threadIdx.x == 0) partial[blockIdx.x] = red[0];
}

__global__ __launch_bounds__(BLOCK) void partial_loss_finalize(
    const float* __restrict__ partial,
    int nparts,
    float* __restrict__ out,
    float inv_n)
{
    __shared__ double red[BLOCK];
    double acc = 0.0;
    for (int i = threadIdx.x; i < nparts; i += BLOCK) acc += (double)partial[i];
    red[threadIdx.x] = acc;
    __syncthreads();
    #pragma unroll
    for (int off = BLOCK / 2; off > 0; off >>= 1) {
        if (threadIdx.x < off) red[threadIdx.x] += red[threadIdx.x + off];
        __syncthreads();
    }
    if (threadIdx.x == 0) out[0] = (float)(red[0] * (double)inv_n);
}

extern "C" void kernel_launch(void* const* d_in, const int* in_sizes, int n_in,
                              void* d_out, int out_size, void* d_ws, size_t ws_size,
                              hipStream_t stream)
{
    const float* predict = (const float*)d_in[0];
    const int*   target  = (const int*)d_in[1];
    const int*   loc_b   = (const int*)d_in[2];
    const int*   loc_row = (const int*)d_in[3];
    const int*   loc_col = (const int*)d_in[4];
    float* out = (float*)d_out;

    int n = in_sizes[2];                         // N = 500000
    int nblocks = (n + BLOCK - 1) / BLOCK;       // 1954

    size_t table_bytes = (size_t)TOTAL_POS * sizeof(float);    // 16 MB
    size_t partial_bytes = (size_t)nblocks * sizeof(float);

    if (ws_size >= table_bytes + partial_bytes) {
        float* table   = (float*)d_ws;
        float* partial = (float*)((char*)d_ws + table_bytes);
        int tblocks = TOTAL_POS / (BLOCK * 4);                 // 4096, exact
        nll_table_v4<<<tblocks, BLOCK, 0, stream>>>(predict, target, table);
        table_gather_kernel<<<nblocks, BLOCK, 0, stream>>>(
            table, loc_b, loc_row, loc_col, partial, n);
        partial_loss_finalize<<<1, BLOCK, 0, stream>>>(
            partial, nblocks, out, 1.0f / (float)n);
    } else {
        float* partial = (float*)d_ws;
        partial_loss_gather<<<nblocks, BLOCK, 0, stream>>>(
            predict, target, loc_b, loc_row, loc_col, partial, n);
        partial_loss_finalize<<<1, BLOCK, 0, stream>>>(
            partial, nblocks, out, 1.0f / (float)n);
    }
}

// Round 7
// 95.341 us; speedup vs baseline: 1.0134x; 1.0134x over previous
//
#include <hip/hip_runtime.h>

// Problem: B=4, C=19, H=1024, W=1024, N=500000
// out = mean_n [ log(sum_j exp(p_j)) - p_label ],  p = softmax(predict[b,:,r,c])
//
// Structure (round 7 = round-3 scalar structure + chunk-mask skipping):
//   (M0) clear 256KB chunk mask, (M1) scatter-set mask from loc arrays
//   (A) coalesced scalar streaming pass computes nll ONLY for positions whose
//       64B line-chunk (16 positions) is touched -> per-lane predication
//       skips ~15% of predict/target fetch and table write
//   (B) random 4B gather from table + block reduce, (C) finalize.
//
// Round-5/6 lessons: float4 (w/ or w/o NT) regressed A (87.8 -> 94.5/96.6 us):
// xs[4][19] costs ~150 VGPR -> occupancy 32->8 waves/CU; scalar x[19] at ~24
// VGPR keeps 32 waves/CU and loads are already wave-coalesced. TLP wins.
//
// NOTE: harness ABI passes ALL integer inputs as int32.

#define CCH 19
#define BLOCK 256
#define POS_BITS 20               // H*W = 1<<20
#define TOTAL_POS (4 << POS_BITS) // B * H * W = 4M
#define NCHUNK (TOTAL_POS >> 4)   // 262144 chunks of 16 positions (64B lines)

__device__ __forceinline__ float nll_compute(float* __restrict__ x, int label)
{
    float m = x[0];
    #pragma unroll
    for (int j = 1; j < CCH; ++j) m = fmaxf(m, x[j]);

    float s = 0.0f, e_label = 0.0f;
    #pragma unroll
    for (int j = 0; j < CCH; ++j) {
        float e = __expf(x[j] - m);
        s += e;
        if (j == label) e_label = e;   // static j vs runtime label -> cndmask
        x[j] = e;
    }
    float inv = 1.0f / s;

    float s2 = 0.0f;
    #pragma unroll
    for (int j = 0; j < CCH; ++j) s2 += __expf(x[j] * inv);

    return __logf(s2) - e_label * inv;
}

// ---- M0: clear mask (d_ws is poisoned 0xAA; must zero each call) ----
__global__ __launch_bounds__(BLOCK) void clear_mask(unsigned int* __restrict__ mask32)
{
    int i = blockIdx.x * blockDim.x + threadIdx.x;   // NCHUNK/4 words
    mask32[i] = 0u;
}

// ---- M1: scatter-set touched chunks (races benign: constant value) ----
__global__ __launch_bounds__(BLOCK) void build_mask(
    const int* __restrict__ loc_b,
    const int* __restrict__ loc_row,
    const int* __restrict__ loc_col,
    unsigned char* __restrict__ mask,
    int n)
{
    int i = blockIdx.x * blockDim.x + threadIdx.x;
    if (i < n) {
        int idx = (loc_b[i] << POS_BITS) + (loc_row[i] << 10) + loc_col[i];
        mask[idx >> 4] = 1;
    }
}

// ---- kernel A: masked scalar nll table (1 thread = 1 position) ----
__global__ __launch_bounds__(BLOCK) void nll_table_masked(
    const float* __restrict__ predict,
    const int* __restrict__ target,
    const unsigned char* __restrict__ mask,
    float* __restrict__ table)
{
    int i = blockIdx.x * blockDim.x + threadIdx.x;   // i = b*HW + pos, coalesced
    if (!mask[i >> 4]) return;                       // lane-predicated: untouched
                                                     // 64B chunks never fetched
    int b = i >> POS_BITS;
    int pos = i & ((1 << POS_BITS) - 1);
    const float* base = predict + (((size_t)b * CCH) << POS_BITS) + (size_t)pos;

    float x[CCH];
    #pragma unroll
    for (int j = 0; j < CCH; ++j) x[j] = base[(size_t)j << POS_BITS];

    table[i] = nll_compute(x, target[i]);
}

// ---- kernel B: random 4B gather from table + block reduce ----
__global__ __launch_bounds__(BLOCK) void table_gather_kernel(
    const float* __restrict__ table,
    const int* __restrict__ loc_b,
    const int* __restrict__ loc_row,
    const int* __restrict__ loc_col,
    float* __restrict__ partial,
    int n)
{
    int i = blockIdx.x * blockDim.x + threadIdx.x;
    float nll = 0.0f;
    if (i < n) {
        int idx = (loc_b[i] << POS_BITS) + (loc_row[i] << 10) + loc_col[i];
        nll = table[idx];
    }
    __shared__ float red[BLOCK];
    red[threadIdx.x] = nll;
    __syncthreads();
    #pragma unroll
    for (int off = BLOCK / 2; off > 0; off >>= 1) {
        if (threadIdx.x < off) red[threadIdx.x] += red[threadIdx.x + off];
        __syncthreads();
    }
    if (threadIdx.x == 0) partial[blockIdx.x] = red[0];
}

// ---- fallback: direct random gather (round-2 path), used if ws too small ----
__global__ __launch_bounds__(BLOCK) void partial_loss_gather(
    const float* __restrict__ predict,
    const int* __restrict__ target,
    const int* __restrict__ loc_b,
    const int* __restrict__ loc_row,
    const int* __restrict__ loc_col,
    float* __restrict__ partial,
    int n)
{
    int i = blockIdx.x * blockDim.x + threadIdx.x;
    float nll = 0.0f;
    if (i < n) {
        int b = loc_b[i];
        int pos = (loc_row[i] << 10) + loc_col[i];
        const float* base = predict + (((size_t)b * CCH) << POS_BITS) + (size_t)pos;
        int label = target[((size_t)b << POS_BITS) + (size_t)pos];
        float x[CCH];
        #pragma unroll
        for (int j = 0; j < CCH; ++j) x[j] = base[(size_t)j << POS_BITS];
        nll = nll_compute(x, label);
    }
    __shared__ float red[BLOCK];
    red[threadIdx.x] = nll;
    __syncthreads();
    #pragma unroll
    for (int off = BLOCK / 2; off > 0; off >>= 1) {
        if (threadIdx.x < off) red[threadIdx.x] += red[threadIdx.x + off];
        __syncthreads();
    }
    if (threadIdx.x == 0) partial[blockIdx.x] = red[0];
}

__global__ __launch_bounds__(BLOCK) void partial_loss_finalize(
    const float* __restrict__ partial,
    int nparts,
    float* __restrict__ out,
    float inv_n)
{
    __shared__ double red[BLOCK];
    double acc = 0.0;
    for (int i = threadIdx.x; i < nparts; i += BLOCK) acc += (double)partial[i];
    red[threadIdx.x] = acc;
    __syncthreads();
    #pragma unroll
    for (int off = BLOCK / 2; off > 0; off >>= 1) {
        if (threadIdx.x < off) red[threadIdx.x] += red[threadIdx.x + off];
        __syncthreads();
    }
    if (threadIdx.x == 0) out[0] = (float)(red[0] * (double)inv_n);
}

extern "C" void kernel_launch(void* const* d_in, const int* in_sizes, int n_in,
                              void* d_out, int out_size, void* d_ws, size_t ws_size,
                              hipStream_t stream)
{
    const float* predict = (const float*)d_in[0];
    const int*   target  = (const int*)d_in[1];
    const int*   loc_b   = (const int*)d_in[2];
    const int*   loc_row = (const int*)d_in[3];
    const int*   loc_col = (const int*)d_in[4];
    float* out = (float*)d_out;

    int n = in_sizes[2];                         // N = 500000
    int nblocks = (n + BLOCK - 1) / BLOCK;       // 1954

    size_t table_bytes   = (size_t)TOTAL_POS * sizeof(float);   // 16 MB
    size_t partial_bytes = (size_t)((nblocks + 63) & ~63) * sizeof(float);
    size_t mask_bytes    = (size_t)NCHUNK;                      // 256 KB

    if (ws_size >= table_bytes + partial_bytes + mask_bytes) {
        float*         table   = (float*)d_ws;
        float*         partial = (float*)((char*)d_ws + table_bytes);
        unsigned char* mask    = (unsigned char*)d_ws + table_bytes + partial_bytes;

        clear_mask<<<NCHUNK / 4 / BLOCK, BLOCK, 0, stream>>>((unsigned int*)mask);
        build_mask<<<nblocks, BLOCK, 0, stream>>>(loc_b, loc_row, loc_col, mask, n);
        nll_table_masked<<<TOTAL_POS / BLOCK, BLOCK, 0, stream>>>(
            predict, target, mask, table);
        table_gather_kernel<<<nblocks, BLOCK, 0, stream>>>(
            table, loc_b, loc_row, loc_col, partial, n);
        partial_loss_finalize<<<1, BLOCK, 0, stream>>>(
            partial, nblocks, out, 1.0f / (float)n);
    } else {
        float* partial = (float*)d_ws;
        partial_loss_gather<<<nblocks, BLOCK, 0, stream>>>(
            predict, target, loc_b, loc_row, loc_col, partial, n);
        partial_loss_finalize<<<1, BLOCK, 0, stream>>>(
            partial, nblocks, out, 1.0f / (float)n);
    }
}